// Round 9
// baseline (230.234 us; speedup 1.0000x reference)
//
#include <hip/hip_runtime.h>

typedef __bf16 bf16x8 __attribute__((ext_vector_type(8)));
typedef float f32x4 __attribute__((ext_vector_type(4)));

#define DI __device__ __forceinline__

// Pinned counted waitcnt (GEMM staging): memory clobber + sched_barrier so
// global_load_lds intrinsics cannot be reordered around it (rule #18).
#define WAIT_VMCNT(N)                                        \
  do {                                                       \
    __builtin_amdgcn_sched_barrier(0);                       \
    asm volatile("s_waitcnt vmcnt(" #N ")" ::: "memory");    \
    __builtin_amdgcn_sched_barrier(0);                       \
  } while (0)

DI unsigned short f2bf(float f) {
  unsigned int u = __float_as_uint(f);
  u += 0x7FFFu + ((u >> 16) & 1u);
  return (unsigned short)(u >> 16);
}

DI unsigned cvt_pk_bf16(float a, float b) {  // lo=bf16(a), hi=bf16(b)
  unsigned r;
  asm("v_cvt_pk_bf16_f32 %0, %1, %2" : "=v"(r) : "v"(a), "v"(b));
  return r;
}

DI float exp2_fast(float x) {  // raw v_exp_f32 (2^x); exp2(-inf)=0
  float r;
  asm("v_exp_f32 %0, %1" : "=v"(r) : "v"(x));
  return r;
}

DI void fence() { asm volatile("" ::: "memory"); }
DI void bar() { fence(); __builtin_amdgcn_s_barrier(); fence(); }

DI bf16x8 ld16(const void* p) {
  union { uint4 u; bf16x8 b; } c;
  c.u = *reinterpret_cast<const uint4*>(p);
  return c.b;
}

DI f32x4 mfma16(bf16x8 a, bf16x8 b, f32x4 c) {
  return __builtin_amdgcn_mfma_f32_16x16x32_bf16(a, b, c, 0, 0, 0);
}

DI void gload_lds16(const void* g, void* l) {
  __builtin_amdgcn_global_load_lds(
      (const __attribute__((address_space(1))) unsigned int*)g,
      (__attribute__((address_space(3))) unsigned int*)l, 16, 0, 0);
}

// ---------------- fused fp32 -> bf16 convert (x, w_qkv, w_proj) ----------------
__global__ void cvt_all(const float* __restrict__ x, const float* __restrict__ wq,
                        const float* __restrict__ wp,
                        unsigned short* __restrict__ xb, unsigned short* __restrict__ wqb,
                        unsigned short* __restrict__ wpb) {
  int i = blockIdx.x * blockDim.x + threadIdx.x;  // float4 index
  const float* s;
  unsigned short* d;
  int off;
  if (i < 2097152) { s = x; d = xb; off = i; }
  else if (i < 2097152 + 786432) { s = wq; d = wqb; off = i - 2097152; }
  else { s = wp; d = wpb; off = i - (2097152 + 786432); }
  float4 v = reinterpret_cast<const float4*>(s)[off];
  uint2 o;
  o.x = cvt_pk_bf16(v.x, v.y);
  o.y = cvt_pk_bf16(v.z, v.w);
  reinterpret_cast<uint2*>(d)[off] = o;
}

// ---------------- GEMM: C[M,N] = A[M,K] * W[N,K]^T + bias ----------------
// PROVEN round-1 structure: 128x128 tile, BK=64, 4 waves (2x2), single-buffered
// LDS (A 16K | B 16K), full drain + barrier per K-step. XOR bank-swizzle on the
// pre-swizzled global source + again on ds_read (involution).
// MODE 0: out = fp32 row-major [M][N] (+bias)
// MODE 1: qkv scatter -> Q (scaled log2e/8), K head-major; V transposed [bh][d][t]
//         (V^T stores packed as uint2: in-lane r's are 4 consecutive t)
template <int N, int MODE>
__global__ __launch_bounds__(256)
void gemm_bt(const unsigned short* __restrict__ A,
             const unsigned short* __restrict__ W,
             const float* __restrict__ bias,
             float* __restrict__ out,
             unsigned short* __restrict__ qo,
             unsigned short* __restrict__ ko,
             unsigned short* __restrict__ vo) {
  constexpr int K = 1024;
  __shared__ __align__(16) char smem[32768];  // A tile 16K | B tile 16K
  char* Asm = smem;
  char* Bsm = smem + 16384;
  const int tid = threadIdx.x;
  const int ln = tid & 63;
  const int w  = tid >> 6;
  const int wm = w >> 1, wn = w & 1;
  const int g = ln >> 4, q = ln & 15;
  const int m0 = blockIdx.x * 128;
  const int n0 = blockIdx.y * 128;

  f32x4 acc[4][4] = {};

  for (int kt = 0; kt < K / 64; ++kt) {
    if (kt) bar();  // previous compute's LDS reads done before overwrite
#pragma unroll
    for (int i = 0; i < 4; ++i) {
      const int chunk = i * 4 + w;                 // [0,16): full 16 KB tile
      const int o = chunk * 1024 + ln * 16;
      const int row = o >> 7;
      const int colb = (o & 127) ^ ((row & 7) << 4);
      gload_lds16((const char*)A + ((size_t)(m0 + row) * K + kt * 64) * 2 + colb,
                  Asm + chunk * 1024);
      gload_lds16((const char*)W + ((size_t)(n0 + row) * K + kt * 64) * 2 + colb,
                  Bsm + chunk * 1024);
    }
    WAIT_VMCNT(0);
    bar();
#pragma unroll
    for (int ks = 0; ks < 2; ++ks) {
      bf16x8 av[4], bv[4];
#pragma unroll
      for (int mf = 0; mf < 4; ++mf) {
        const int row = wm * 64 + mf * 16 + q;
        av[mf] = ld16(Asm + ((row * 128 + ks * 64 + g * 16) ^ ((row & 7) << 4)));
      }
#pragma unroll
      for (int nf = 0; nf < 4; ++nf) {
        const int row = wn * 64 + nf * 16 + q;
        bv[nf] = ld16(Bsm + ((row * 128 + ks * 64 + g * 16) ^ ((row & 7) << 4)));
      }
#pragma unroll
      for (int mf = 0; mf < 4; ++mf)
#pragma unroll
        for (int nf = 0; nf < 4; ++nf)
          acc[mf][nf] = mfma16(av[mf], bv[nf], acc[mf][nf]);
    }
  }

#pragma unroll
  for (int nf = 0; nf < 4; ++nf) {
    const int col = n0 + wn * 64 + nf * 16 + q;
    const float bv = bias[col];
#pragma unroll
    for (int mf = 0; mf < 4; ++mf) {
      const int rbase = m0 + wm * 64 + mf * 16 + g * 4;
      if constexpr (MODE == 0) {
#pragma unroll
        for (int r = 0; r < 4; ++r)
          out[(size_t)(rbase + r) * N + col] = acc[mf][nf][r] + bv;
      } else {
        const int b = rbase >> 11, t0 = rbase & 2047;  // 4 consecutive t, same b
        if (col < 1024) {
          const int h = col >> 6, d = col & 63;
          unsigned short* qp = qo + ((((size_t)b * 16 + h) << 11) + t0) * 64 + d;
#pragma unroll
          for (int r = 0; r < 4; ++r)
            qp[r * 64] = f2bf((acc[mf][nf][r] + bv) * 0.18033688011112042f);
        } else if (col < 2048) {
          const int c = col - 1024;
          const int h = c >> 6, d = c & 63;
          unsigned short* kp = ko + ((((size_t)b * 16 + h) << 11) + t0) * 64 + d;
#pragma unroll
          for (int r = 0; r < 4; ++r)
            kp[r * 64] = f2bf(acc[mf][nf][r] + bv);
        } else {
          const int c = col - 2048;
          const int h = c >> 6, d = c & 63;
          uint2 pk;
          pk.x = cvt_pk_bf16(acc[mf][nf][0] + bv, acc[mf][nf][1] + bv);
          pk.y = cvt_pk_bf16(acc[mf][nf][2] + bv, acc[mf][nf][3] + bv);
          *(uint2*)(vo + ((((size_t)b * 16 + h) << 6) + d) * 2048 + t0) = pk;
        }
      }
    }
  }
}

// ---------------- flash attention (causal), BARRIER-FREE, L2-direct ----------------
// K/V panels are L2-resident (FETCH 30MB measured vs 110MB logical) -> don't stage
// them (common-mistake #7). Each wave reads K and V^T MFMA fragments DIRECTLY from
// global (same per-lane fragment math as the old LDS reads, no swizzle). P lives in
// a private 4KB/wave LDS slice (same-wave write->read: lgkmcnt only). ZERO barriers;
// each wave ends its kv loop at its own diagonal: nkv = ((qw+31)>>6)+1.
// launch_bounds(256,3) targets >=3 waves/SIMD residency. Grid (bh=64, qt=16),
// qt = QMAP[by] heavy-first (LPT).
__global__ __launch_bounds__(256, 3)
void attn_fwd(const unsigned short* __restrict__ Qb,
              const unsigned short* __restrict__ Kb,
              const unsigned short* __restrict__ Vtb,
              unsigned short* __restrict__ Yb) {
  __shared__ __align__(16) char smem[16384];  // 4 waves x 4KB private P
  const int tid = threadIdx.x;
  const int ln = tid & 63;
  const int w = tid >> 6;
  const int g = ln >> 4, q = ln & 15;
  char* Psm = smem + w * 4096;  // [32 rows][64 kv] bf16, XOR-swizzled rows
  const int bh = blockIdx.x;
  __constant__ static const int QMAP[16] = {15, 14, 13, 12, 8, 9, 10, 11,
                                            4, 5, 6, 7, 3, 2, 1, 0};
  const int qt = QMAP[blockIdx.y];
  const size_t base = (size_t)bh * 2048 * 64;  // elements
  const int b = bh >> 4, h = bh & 15;
  const int qw = qt * 128 + w * 32;

  bf16x8 qf[2][2];
#pragma unroll
  for (int nf = 0; nf < 2; ++nf)
#pragma unroll
    for (int kf = 0; kf < 2; ++kf)
      qf[nf][kf] = ld16(Qb + base + (size_t)(qw + nf * 16 + q) * 64 + kf * 32 + g * 8);

  float m_run[2] = {-INFINITY, -INFINITY};
  float l_run[2] = {0.f, 0.f};
  f32x4 yt[4][2] = {};

  // hoistable per-lane bases
  const char* Kl = (const char*)(Kb + base + (size_t)q * 64) + g * 16;       // + kvrow*128 + ks*64
  const char* Vl = (const char*)(Vtb + base + (size_t)q * 2048) + g * 16;    // + drow*4096 + kv0*2 + kf*64

  const int nkv = ((qw + 31) >> 6) + 1;  // this wave's own diagonal bound
  for (int j = 0; j < nkv; ++j) {
    const int kv0 = j << 6;
    // ---- QK^T: A = K fragments straight from L2 ----
    f32x4 st[4][2] = {};
    __builtin_amdgcn_s_setprio(1);
#pragma unroll
    for (int mf = 0; mf < 4; ++mf) {
      const char* kp = Kl + (size_t)(kv0 + mf * 16) * 128;
      const bf16x8 a0 = ld16(kp);
      const bf16x8 a1 = ld16(kp + 64);
#pragma unroll
      for (int nf = 0; nf < 2; ++nf) {
        st[mf][nf] = mfma16(a0, qf[nf][0], st[mf][nf]);
        st[mf][nf] = mfma16(a1, qf[nf][1], st[mf][nf]);
      }
    }
    __builtin_amdgcn_s_setprio(0);
    if (kv0 + 63 > qw) {  // diagonal tile: causal mask
#pragma unroll
      for (int mf = 0; mf < 4; ++mf)
#pragma unroll
        for (int nf = 0; nf < 2; ++nf)
#pragma unroll
          for (int r = 0; r < 4; ++r)
            if (kv0 + mf * 16 + g * 4 + r > qw + nf * 16 + q)
              st[mf][nf][r] = -INFINITY;
    }
    // ---- online softmax (base-2 domain; Q pre-scaled log2e/8) ----
#pragma unroll
    for (int nf = 0; nf < 2; ++nf) {
      float vmax = -INFINITY;
#pragma unroll
      for (int mf = 0; mf < 4; ++mf) {
        const f32x4 v = st[mf][nf];
        vmax = fmaxf(fmaxf(vmax, fmaxf(v[0], v[1])), fmaxf(v[2], v[3]));
      }
      vmax = fmaxf(vmax, __shfl_xor(vmax, 16));
      vmax = fmaxf(vmax, __shfl_xor(vmax, 32));
      const float mo = m_run[nf];
      if (__any(vmax > mo)) {  // exact skip: if no lane grows, corr == 1 exactly
        const float mn = fmaxf(mo, vmax);
        const float corr = exp2_fast(mo - mn);
        m_run[nf] = mn;
        l_run[nf] *= corr;
#pragma unroll
        for (int mfd = 0; mfd < 4; ++mfd) yt[mfd][nf] *= corr;
      }
      const float mcur = m_run[nf];
      float ls = 0.f;
#pragma unroll
      for (int mf = 0; mf < 4; ++mf) {
        f32x4 p;
#pragma unroll
        for (int r = 0; r < 4; ++r) p[r] = exp2_fast(st[mf][nf][r] - mcur);
        ls += (p[0] + p[1]) + (p[2] + p[3]);
        uint2 pk2;
        pk2.x = cvt_pk_bf16(p[0], p[1]);
        pk2.y = cvt_pk_bf16(p[2], p[3]);
        const int prow = nf * 16 + q;  // private slice: rows 0..31
        *(uint2*)(Psm + ((prow * 128 + mf * 32 + g * 8) ^ ((prow & 7) << 4))) = pk2;
      }
      ls += __shfl_xor(ls, 16);
      ls += __shfl_xor(ls, 32);
      l_run[nf] += ls;
    }
    // same-wave P write -> read ordering (rule #18)
    asm volatile("s_waitcnt lgkmcnt(0)" ::: "memory");
    __builtin_amdgcn_sched_barrier(0);
    // ---- PV: Y^T += Vt * P^T ; A = V^T fragments straight from L2 ----
    __builtin_amdgcn_s_setprio(1);
#pragma unroll
    for (int kf = 0; kf < 2; ++kf) {
      bf16x8 pb[2];
#pragma unroll
      for (int nf = 0; nf < 2; ++nf) {
        const int prow = nf * 16 + q;
        pb[nf] = ld16(Psm + ((prow * 128 + kf * 64 + g * 16) ^ ((prow & 7) << 4)));
      }
#pragma unroll
      for (int mfd = 0; mfd < 4; ++mfd) {
        const bf16x8 vv = ld16(Vl + (size_t)(mfd * 16) * 4096 + kv0 * 2 + kf * 64);
#pragma unroll
        for (int nf = 0; nf < 2; ++nf)
          yt[mfd][nf] = mfma16(vv, pb[nf], yt[mfd][nf]);
      }
    }
    __builtin_amdgcn_s_setprio(0);
  }

#pragma unroll
  for (int nf = 0; nf < 2; ++nf) {
    const float inv = 1.f / l_run[nf];
    const int qr = qw + nf * 16 + q;
    unsigned short* yp = Yb + (size_t)(b * 2048 + qr) * 1024 + h * 64;
#pragma unroll
    for (int mfd = 0; mfd < 4; ++mfd) {
      uint2 o2;
      o2.x = cvt_pk_bf16(yt[mfd][nf][0] * inv, yt[mfd][nf][1] * inv);
      o2.y = cvt_pk_bf16(yt[mfd][nf][2] * inv, yt[mfd][nf][3] * inv);
      *(uint2*)(yp + mfd * 16 + g * 4) = o2;
    }
  }
}

extern "C" void kernel_launch(void* const* d_in, const int* in_sizes, int n_in,
                              void* d_out, int out_size, void* d_ws, size_t ws_size,
                              hipStream_t stream) {
  const float* x      = (const float*)d_in[0];
  const float* w_qkv  = (const float*)d_in[1];
  const float* b_qkv  = (const float*)d_in[2];
  const float* w_proj = (const float*)d_in[3];
  const float* b_proj = (const float*)d_in[4];
  float* out = (float*)d_out;
  char* ws = (char*)d_ws;

  unsigned short* xb  = (unsigned short*)(ws);                       // 16 MB x bf16
  unsigned short* wqb = (unsigned short*)(ws + (size_t)(16 << 20));  //  6 MB w_qkv bf16
  unsigned short* wpb = (unsigned short*)(ws + (size_t)(22 << 20));  //  2 MB w_proj bf16
  unsigned short* Qb  = (unsigned short*)(ws + (size_t)(24 << 20));  // 16 MB Q (pre-scaled log2e/8)
  unsigned short* Kb  = (unsigned short*)(ws + (size_t)(40 << 20));  // 16 MB K [bh][t][d]
  unsigned short* Vtb = (unsigned short*)(ws + (size_t)(56 << 20));  // 16 MB V^T [bh][d][t]
  unsigned short* Yb  = (unsigned short*)(ws + (size_t)(72 << 20));  // 16 MB attn out bf16

  cvt_all<<<12288, 256, 0, stream>>>(x, w_qkv, w_proj, xb, wqb, wpb);
  gemm_bt<3072, 1><<<dim3(64, 24), 256, 0, stream>>>(xb, wqb, b_qkv, nullptr, Qb, Kb, Vtb);
  attn_fwd<<<dim3(64, 16), 256, 0, stream>>>(Qb, Kb, Vtb, Yb);
  gemm_bt<1024, 0><<<dim3(64, 8), 256, 0, stream>>>(Yb, wpb, b_proj, out, nullptr, nullptr, nullptr);
}

// Round 10
// 167.044 us; speedup vs baseline: 1.3783x; 1.3783x over previous
//
#include <hip/hip_runtime.h>

typedef __bf16 bf16x8 __attribute__((ext_vector_type(8)));
typedef float f32x4 __attribute__((ext_vector_type(4)));

#define DI __device__ __forceinline__

// Pinned counted waitcnt: memory clobber + sched_barrier so global_load_lds
// intrinsics cannot be reordered around it (rule #18).
#define WAIT_VMCNT(N)                                        \
  do {                                                       \
    __builtin_amdgcn_sched_barrier(0);                       \
    asm volatile("s_waitcnt vmcnt(" #N ")" ::: "memory");    \
    __builtin_amdgcn_sched_barrier(0);                       \
  } while (0)

DI unsigned short f2bf(float f) {
  unsigned int u = __float_as_uint(f);
  u += 0x7FFFu + ((u >> 16) & 1u);
  return (unsigned short)(u >> 16);
}

DI unsigned cvt_pk_bf16(float a, float b) {  // lo=bf16(a), hi=bf16(b)
  unsigned r;
  asm("v_cvt_pk_bf16_f32 %0, %1, %2" : "=v"(r) : "v"(a), "v"(b));
  return r;
}

DI float exp2_fast(float x) {  // raw v_exp_f32 (2^x); exp2(-inf)=0
  float r;
  asm("v_exp_f32 %0, %1" : "=v"(r) : "v"(x));
  return r;
}

DI void fence() { asm volatile("" ::: "memory"); }
DI void bar() { fence(); __builtin_amdgcn_s_barrier(); fence(); }

DI bf16x8 ld16(const void* p) {
  union { uint4 u; bf16x8 b; } c;
  c.u = *reinterpret_cast<const uint4*>(p);
  return c.b;
}

DI f32x4 mfma16(bf16x8 a, bf16x8 b, f32x4 c) {
  return __builtin_amdgcn_mfma_f32_16x16x32_bf16(a, b, c, 0, 0, 0);
}

DI void gload_lds16(const void* g, void* l) {
  __builtin_amdgcn_global_load_lds(
      (const __attribute__((address_space(1))) unsigned int*)g,
      (__attribute__((address_space(3))) unsigned int*)l, 16, 0, 0);
}

// ---------------- fused fp32 -> bf16 convert (x, w_qkv, w_proj) ----------------
__global__ void cvt_all(const float* __restrict__ x, const float* __restrict__ wq,
                        const float* __restrict__ wp,
                        unsigned short* __restrict__ xb, unsigned short* __restrict__ wqb,
                        unsigned short* __restrict__ wpb) {
  int i = blockIdx.x * blockDim.x + threadIdx.x;  // float4 index
  const float* s;
  unsigned short* d;
  int off;
  if (i < 2097152) { s = x; d = xb; off = i; }
  else if (i < 2097152 + 786432) { s = wq; d = wqb; off = i - 2097152; }
  else { s = wp; d = wpb; off = i - (2097152 + 786432); }
  float4 v = reinterpret_cast<const float4*>(s)[off];
  uint2 o;
  o.x = cvt_pk_bf16(v.x, v.y);
  o.y = cvt_pk_bf16(v.z, v.w);
  reinterpret_cast<uint2*>(d)[off] = o;
}

// ---------------- GEMM: C[M,N] = A[M,K] * W[N,K]^T + bias ----------------
// PROVEN round-1 structure: 128x128 tile, BK=64, 4 waves (2x2), single-buffered
// LDS (A 16K | B 16K), full drain + barrier per K-step. XOR bank-swizzle on the
// pre-swizzled global source + again on ds_read (involution).
// MODE 0: out = fp32 row-major [M][N] (+bias)
// MODE 1: qkv scatter -> Q (scaled log2e/8), K head-major; V transposed [bh][d][t]
//         (V^T stores packed as uint2: in-lane r's are 4 consecutive t)
template <int N, int MODE>
__global__ __launch_bounds__(256)
void gemm_bt(const unsigned short* __restrict__ A,
             const unsigned short* __restrict__ W,
             const float* __restrict__ bias,
             float* __restrict__ out,
             unsigned short* __restrict__ qo,
             unsigned short* __restrict__ ko,
             unsigned short* __restrict__ vo) {
  constexpr int K = 1024;
  __shared__ __align__(16) char smem[32768];  // A tile 16K | B tile 16K
  char* Asm = smem;
  char* Bsm = smem + 16384;
  const int tid = threadIdx.x;
  const int ln = tid & 63;
  const int w  = tid >> 6;
  const int wm = w >> 1, wn = w & 1;
  const int g = ln >> 4, q = ln & 15;
  const int m0 = blockIdx.x * 128;
  const int n0 = blockIdx.y * 128;

  f32x4 acc[4][4] = {};

  for (int kt = 0; kt < K / 64; ++kt) {
    if (kt) bar();  // previous compute's LDS reads done before overwrite
#pragma unroll
    for (int i = 0; i < 4; ++i) {
      const int chunk = i * 4 + w;                 // [0,16): full 16 KB tile
      const int o = chunk * 1024 + ln * 16;
      const int row = o >> 7;
      const int colb = (o & 127) ^ ((row & 7) << 4);
      gload_lds16((const char*)A + ((size_t)(m0 + row) * K + kt * 64) * 2 + colb,
                  Asm + chunk * 1024);
      gload_lds16((const char*)W + ((size_t)(n0 + row) * K + kt * 64) * 2 + colb,
                  Bsm + chunk * 1024);
    }
    WAIT_VMCNT(0);
    bar();
#pragma unroll
    for (int ks = 0; ks < 2; ++ks) {
      bf16x8 av[4], bv[4];
#pragma unroll
      for (int mf = 0; mf < 4; ++mf) {
        const int row = wm * 64 + mf * 16 + q;
        av[mf] = ld16(Asm + ((row * 128 + ks * 64 + g * 16) ^ ((row & 7) << 4)));
      }
#pragma unroll
      for (int nf = 0; nf < 4; ++nf) {
        const int row = wn * 64 + nf * 16 + q;
        bv[nf] = ld16(Bsm + ((row * 128 + ks * 64 + g * 16) ^ ((row & 7) << 4)));
      }
#pragma unroll
      for (int mf = 0; mf < 4; ++mf)
#pragma unroll
        for (int nf = 0; nf < 4; ++nf)
          acc[mf][nf] = mfma16(av[mf], bv[nf], acc[mf][nf]);
    }
  }

#pragma unroll
  for (int nf = 0; nf < 4; ++nf) {
    const int col = n0 + wn * 64 + nf * 16 + q;
    const float bv = bias[col];
#pragma unroll
    for (int mf = 0; mf < 4; ++mf) {
      const int rbase = m0 + wm * 64 + mf * 16 + g * 4;
      if constexpr (MODE == 0) {
#pragma unroll
        for (int r = 0; r < 4; ++r)
          out[(size_t)(rbase + r) * N + col] = acc[mf][nf][r] + bv;
      } else {
        const int b = rbase >> 11, t0 = rbase & 2047;  // 4 consecutive t, same b
        if (col < 1024) {
          const int h = col >> 6, d = col & 63;
          unsigned short* qp = qo + ((((size_t)b * 16 + h) << 11) + t0) * 64 + d;
#pragma unroll
          for (int r = 0; r < 4; ++r)
            qp[r * 64] = f2bf((acc[mf][nf][r] + bv) * 0.18033688011112042f);
        } else if (col < 2048) {
          const int c = col - 1024;
          const int h = c >> 6, d = c & 63;
          unsigned short* kp = ko + ((((size_t)b * 16 + h) << 11) + t0) * 64 + d;
#pragma unroll
          for (int r = 0; r < 4; ++r)
            kp[r * 64] = f2bf(acc[mf][nf][r] + bv);
        } else {
          const int c = col - 2048;
          const int h = c >> 6, d = c & 63;
          uint2 pk;
          pk.x = cvt_pk_bf16(acc[mf][nf][0] + bv, acc[mf][nf][1] + bv);
          pk.y = cvt_pk_bf16(acc[mf][nf][2] + bv, acc[mf][nf][3] + bv);
          *(uint2*)(vo + ((((size_t)b * 16 + h) << 6) + d) * 2048 + t0) = pk;
        }
      }
    }
  }
}

// ---------------- flash attention (causal), QBLK=64, dbuf, pair-balanced ----------------
// Proven r7 pipeline (K/V dbuf in LDS, counted vmcnt(4), swapped QK^T, swizzled P)
// with a SMALLER WORK QUANTUM: 4 waves x 16 q-rows = 64 q-rows/block.
// LDS = 32K dbuf + 8K P = 40KB -> 4 blocks/CU; launch_bounds(256,4) -> 4 waves/SIMD.
// Grid (bh=64, pair=16): block runs q-tiles {31-p, p}; iters = (32-p)+(p+2) = 34
// for EVERY block -> 1024 identical blocks, all resident (4/CU), zero drain.
__global__ __launch_bounds__(256, 4)
void attn_fwd(const unsigned short* __restrict__ Qb,
              const unsigned short* __restrict__ Kb,
              const unsigned short* __restrict__ Vtb,
              unsigned short* __restrict__ Yb) {
  __shared__ __align__(16) char smem[40960];
  // buf0: K [0,8K) V [8K,16K); buf1: K [16K,24K) V [24K,32K); P [32K,40K) (2K/wave)
  const int tid = threadIdx.x;
  const int ln = tid & 63;
  const int w = tid >> 6;
  const int g = ln >> 4, q = ln & 15;
  char* Psm = smem + 32768 + w * 2048;  // [16 q][64 kv] bf16, XOR-swizzled rows
  const int bh = blockIdx.x;
  const int pair = blockIdx.y;
  const size_t base = (size_t)bh * 2048 * 64;  // elements
  const int b = bh >> 4, h = bh & 15;

  auto stage = [&](int j, int buf) {
    char* Kd = smem + buf * 16384;
    char* Vd = Kd + 8192;
    const int kv0 = j << 6;
    const char* Kg = (const char*)(Kb + base + (size_t)kv0 * 64);
    const char* Vg = (const char*)(Vtb + base) + kv0 * 2;
#pragma unroll
    for (int i = 0; i < 2; ++i) {
      const int chunk = i * 4 + w;                 // [0,8): 8 KB per tile
      const int o = chunk * 1024 + ln * 16;
      const int row = o >> 7;
      const int colb = (o & 127) ^ ((row & 7) << 4);
      gload_lds16(Kg + row * 128 + colb, Kd + chunk * 1024);
      gload_lds16(Vg + (size_t)row * 4096 + colb, Vd + chunk * 1024);
    }
  };

  auto run_qtile = [&](int qt) {     // qt in [0,32): 64 q-rows
    const int q0 = qt * 64;
    const int qw = q0 + w * 16;      // this wave's 16 q-rows

    bf16x8 qf[2];
#pragma unroll
    for (int kf = 0; kf < 2; ++kf)
      qf[kf] = ld16(Qb + base + (size_t)(qw + q) * 64 + kf * 32 + g * 8);
    WAIT_VMCNT(0);  // drains Q loads AND prior epilogue stores: counts stay exact

    float m_run = -INFINITY;
    float l_run = 0.f;
    f32x4 yt[4] = {};

    const int nkv = qt + 1;
    stage(0, 0);
    for (int j = 0; j < nkv; ++j) {
      if (j + 1 < nkv) {
        stage(j + 1, (j + 1) & 1);
        WAIT_VMCNT(4);
      } else {
        WAIT_VMCNT(0);
      }
      bar();

      const int kv0 = j << 6;
      const char* Ksm = smem + (j & 1) * 16384;
      const char* Vsm = Ksm + 8192;
      // all waves active on every tile (kv0 <= q0 <= qw+15 always)
      f32x4 st[4] = {};
      __builtin_amdgcn_s_setprio(1);
#pragma unroll
      for (int mf = 0; mf < 4; ++mf) {
        const int row = mf * 16 + q;
        const int swz = (row & 7) << 4;
        const bf16x8 a0 = ld16(Ksm + ((row * 128 + g * 16) ^ swz));
        const bf16x8 a1 = ld16(Ksm + ((row * 128 + 64 + g * 16) ^ swz));
        st[mf] = mfma16(a0, qf[0], st[mf]);
        st[mf] = mfma16(a1, qf[1], st[mf]);
      }
      __builtin_amdgcn_s_setprio(0);
      if (kv0 + 63 > qw) {  // diagonal tile: causal mask
#pragma unroll
        for (int mf = 0; mf < 4; ++mf)
#pragma unroll
          for (int r = 0; r < 4; ++r)
            if (kv0 + mf * 16 + g * 4 + r > qw + q)
              st[mf][r] = -INFINITY;
      }
      {
        float vmax = -INFINITY;
#pragma unroll
        for (int mf = 0; mf < 4; ++mf) {
          const f32x4 v = st[mf];
          vmax = fmaxf(fmaxf(vmax, fmaxf(v[0], v[1])), fmaxf(v[2], v[3]));
        }
        vmax = fmaxf(vmax, __shfl_xor(vmax, 16));
        vmax = fmaxf(vmax, __shfl_xor(vmax, 32));
        const float mo = m_run;
        if (__any(vmax > mo)) {  // exact skip: if no lane grows, corr == 1 exactly
          const float mn = fmaxf(mo, vmax);
          const float corr = exp2_fast(mo - mn);
          m_run = mn;
          l_run *= corr;
#pragma unroll
          for (int mfd = 0; mfd < 4; ++mfd) yt[mfd] *= corr;
        }
        const float mcur = m_run;
        float ls = 0.f;
#pragma unroll
        for (int mf = 0; mf < 4; ++mf) {
          f32x4 p;
#pragma unroll
          for (int r = 0; r < 4; ++r) p[r] = exp2_fast(st[mf][r] - mcur);
          ls += (p[0] + p[1]) + (p[2] + p[3]);
          uint2 pk2;
          pk2.x = cvt_pk_bf16(p[0], p[1]);
          pk2.y = cvt_pk_bf16(p[2], p[3]);
          *(uint2*)(Psm + ((q * 128 + mf * 32 + g * 8) ^ ((q & 7) << 4))) = pk2;
        }
        ls += __shfl_xor(ls, 16);
        ls += __shfl_xor(ls, 32);
        l_run += ls;
      }
      // same-wave P write -> read ordering
      asm volatile("s_waitcnt lgkmcnt(0)" ::: "memory");
      __builtin_amdgcn_sched_barrier(0);
      // PV: Y^T[d][q] += Vt * P^T (per-wave P slice)
      __builtin_amdgcn_s_setprio(1);
#pragma unroll
      for (int kf = 0; kf < 2; ++kf) {
        const bf16x8 pb = ld16(Psm + ((q * 128 + kf * 64 + g * 16) ^ ((q & 7) << 4)));
#pragma unroll
        for (int mfd = 0; mfd < 4; ++mfd) {
          const int vrow = mfd * 16 + q;
          const bf16x8 vv = ld16(Vsm + ((vrow * 128 + kf * 64 + g * 16) ^ ((vrow & 7) << 4)));
          yt[mfd] = mfma16(vv, pb, yt[mfd]);
        }
      }
      __builtin_amdgcn_s_setprio(0);
      bar();  // all waves done reading K/V before next stage overwrites
    }

    const float inv = 1.f / l_run;
    const int qr = qw + q;
    unsigned short* yp = Yb + (size_t)(b * 2048 + qr) * 1024 + h * 64;
#pragma unroll
    for (int mfd = 0; mfd < 4; ++mfd) {
      uint2 o2;
      o2.x = cvt_pk_bf16(yt[mfd][0] * inv, yt[mfd][1] * inv);
      o2.y = cvt_pk_bf16(yt[mfd][2] * inv, yt[mfd][3] * inv);
      *(uint2*)(yp + mfd * 16 + g * 4) = o2;
    }
  };

  run_qtile(31 - pair);  // heavy q-tile first: 32-pair iters
  run_qtile(pair);       // light q-tile: pair+2... total = 34 for every block
}

extern "C" void kernel_launch(void* const* d_in, const int* in_sizes, int n_in,
                              void* d_out, int out_size, void* d_ws, size_t ws_size,
                              hipStream_t stream) {
  const float* x      = (const float*)d_in[0];
  const float* w_qkv  = (const float*)d_in[1];
  const float* b_qkv  = (const float*)d_in[2];
  const float* w_proj = (const float*)d_in[3];
  const float* b_proj = (const float*)d_in[4];
  float* out = (float*)d_out;
  char* ws = (char*)d_ws;

  unsigned short* xb  = (unsigned short*)(ws);                       // 16 MB x bf16
  unsigned short* wqb = (unsigned short*)(ws + (size_t)(16 << 20));  //  6 MB w_qkv bf16
  unsigned short* wpb = (unsigned short*)(ws + (size_t)(22 << 20));  //  2 MB w_proj bf16
  unsigned short* Qb  = (unsigned short*)(ws + (size_t)(24 << 20));  // 16 MB Q (pre-scaled log2e/8)
  unsigned short* Kb  = (unsigned short*)(ws + (size_t)(40 << 20));  // 16 MB K [bh][t][d]
  unsigned short* Vtb = (unsigned short*)(ws + (size_t)(56 << 20));  // 16 MB V^T [bh][d][t]
  unsigned short* Yb  = (unsigned short*)(ws + (size_t)(72 << 20));  // 16 MB attn out bf16

  cvt_all<<<12288, 256, 0, stream>>>(x, w_qkv, w_proj, xb, wqb, wpb);
  gemm_bt<3072, 1><<<dim3(64, 24), 256, 0, stream>>>(xb, wqb, b_qkv, nullptr, Qb, Kb, Vtb);
  attn_fwd<<<dim3(64, 16), 256, 0, stream>>>(Qb, Kb, Vtb, Yb);
  gemm_bt<1024, 0><<<dim3(64, 8), 256, 0, stream>>>(Yb, wpb, b_proj, out, nullptr, nullptr, nullptr);
}

// Round 11
// 165.574 us; speedup vs baseline: 1.3905x; 1.0089x over previous
//
#include <hip/hip_runtime.h>

typedef __bf16 bf16x8 __attribute__((ext_vector_type(8)));
typedef float f32x4 __attribute__((ext_vector_type(4)));

#define DI __device__ __forceinline__

// Pinned counted waitcnt: memory clobber + sched_barrier so global_load_lds
// intrinsics cannot be reordered around it (rule #18).
#define WAIT_VMCNT(N)                                        \
  do {                                                       \
    __builtin_amdgcn_sched_barrier(0);                       \
    asm volatile("s_waitcnt vmcnt(" #N ")" ::: "memory");    \
    __builtin_amdgcn_sched_barrier(0);                       \
  } while (0)

DI unsigned short f2bf(float f) {
  unsigned int u = __float_as_uint(f);
  u += 0x7FFFu + ((u >> 16) & 1u);
  return (unsigned short)(u >> 16);
}

DI unsigned cvt_pk_bf16(float a, float b) {  // lo=bf16(a), hi=bf16(b)
  unsigned r;
  asm("v_cvt_pk_bf16_f32 %0, %1, %2" : "=v"(r) : "v"(a), "v"(b));
  return r;
}

DI float exp2_fast(float x) {  // raw v_exp_f32 (2^x); exp2(-inf)=0
  float r;
  asm("v_exp_f32 %0, %1" : "=v"(r) : "v"(x));
  return r;
}

DI void fence() { asm volatile("" ::: "memory"); }
DI void bar() { fence(); __builtin_amdgcn_s_barrier(); fence(); }

DI bf16x8 ld16(const void* p) {
  union { uint4 u; bf16x8 b; } c;
  c.u = *reinterpret_cast<const uint4*>(p);
  return c.b;
}

DI f32x4 mfma16(bf16x8 a, bf16x8 b, f32x4 c) {
  return __builtin_amdgcn_mfma_f32_16x16x32_bf16(a, b, c, 0, 0, 0);
}

DI void gload_lds16(const void* g, void* l) {
  __builtin_amdgcn_global_load_lds(
      (const __attribute__((address_space(1))) unsigned int*)g,
      (__attribute__((address_space(3))) unsigned int*)l, 16, 0, 0);
}

// ---------------- fused fp32 -> bf16 convert (x, w_qkv, w_proj) ----------------
__global__ void cvt_all(const float* __restrict__ x, const float* __restrict__ wq,
                        const float* __restrict__ wp,
                        unsigned short* __restrict__ xb, unsigned short* __restrict__ wqb,
                        unsigned short* __restrict__ wpb) {
  int i = blockIdx.x * blockDim.x + threadIdx.x;  // float4 index
  const float* s;
  unsigned short* d;
  int off;
  if (i < 2097152) { s = x; d = xb; off = i; }
  else if (i < 2097152 + 786432) { s = wq; d = wqb; off = i - 2097152; }
  else { s = wp; d = wpb; off = i - (2097152 + 786432); }
  float4 v = reinterpret_cast<const float4*>(s)[off];
  uint2 o;
  o.x = cvt_pk_bf16(v.x, v.y);
  o.y = cvt_pk_bf16(v.z, v.w);
  reinterpret_cast<uint2*>(d)[off] = o;
}

// ---------------- GEMM: C[M,N] = A[M,K] * W[N,K]^T + bias ----------------
// PROVEN round-1 structure: 128x128 tile, BK=64, 4 waves (2x2), single-buffered
// LDS (A 16K | B 16K), full drain + barrier per K-step. XOR bank-swizzle on the
// pre-swizzled global source + again on ds_read (involution).
// MODE 0: out = fp32 row-major [M][N] (+bias)
// MODE 1: qkv scatter -> Q (scaled log2e/8), K head-major; V transposed [bh][d][t]
//         (V^T stores packed as uint2: in-lane r's are 4 consecutive t)
template <int N, int MODE>
__global__ __launch_bounds__(256)
void gemm_bt(const unsigned short* __restrict__ A,
             const unsigned short* __restrict__ W,
             const float* __restrict__ bias,
             float* __restrict__ out,
             unsigned short* __restrict__ qo,
             unsigned short* __restrict__ ko,
             unsigned short* __restrict__ vo) {
  constexpr int K = 1024;
  __shared__ __align__(16) char smem[32768];  // A tile 16K | B tile 16K
  char* Asm = smem;
  char* Bsm = smem + 16384;
  const int tid = threadIdx.x;
  const int ln = tid & 63;
  const int w  = tid >> 6;
  const int wm = w >> 1, wn = w & 1;
  const int g = ln >> 4, q = ln & 15;
  const int m0 = blockIdx.x * 128;
  const int n0 = blockIdx.y * 128;

  f32x4 acc[4][4] = {};

  for (int kt = 0; kt < K / 64; ++kt) {
    if (kt) bar();  // previous compute's LDS reads done before overwrite
#pragma unroll
    for (int i = 0; i < 4; ++i) {
      const int chunk = i * 4 + w;                 // [0,16): full 16 KB tile
      const int o = chunk * 1024 + ln * 16;
      const int row = o >> 7;
      const int colb = (o & 127) ^ ((row & 7) << 4);
      gload_lds16((const char*)A + ((size_t)(m0 + row) * K + kt * 64) * 2 + colb,
                  Asm + chunk * 1024);
      gload_lds16((const char*)W + ((size_t)(n0 + row) * K + kt * 64) * 2 + colb,
                  Bsm + chunk * 1024);
    }
    WAIT_VMCNT(0);
    bar();
#pragma unroll
    for (int ks = 0; ks < 2; ++ks) {
      bf16x8 av[4], bv[4];
#pragma unroll
      for (int mf = 0; mf < 4; ++mf) {
        const int row = wm * 64 + mf * 16 + q;
        av[mf] = ld16(Asm + ((row * 128 + ks * 64 + g * 16) ^ ((row & 7) << 4)));
      }
#pragma unroll
      for (int nf = 0; nf < 4; ++nf) {
        const int row = wn * 64 + nf * 16 + q;
        bv[nf] = ld16(Bsm + ((row * 128 + ks * 64 + g * 16) ^ ((row & 7) << 4)));
      }
#pragma unroll
      for (int mf = 0; mf < 4; ++mf)
#pragma unroll
        for (int nf = 0; nf < 4; ++nf)
          acc[mf][nf] = mfma16(av[mf], bv[nf], acc[mf][nf]);
    }
  }

#pragma unroll
  for (int nf = 0; nf < 4; ++nf) {
    const int col = n0 + wn * 64 + nf * 16 + q;
    const float bv = bias[col];
#pragma unroll
    for (int mf = 0; mf < 4; ++mf) {
      const int rbase = m0 + wm * 64 + mf * 16 + g * 4;
      if constexpr (MODE == 0) {
#pragma unroll
        for (int r = 0; r < 4; ++r)
          out[(size_t)(rbase + r) * N + col] = acc[mf][nf][r] + bv;
      } else {
        const int b = rbase >> 11, t0 = rbase & 2047;  // 4 consecutive t, same b
        if (col < 1024) {
          const int h = col >> 6, d = col & 63;
          unsigned short* qp = qo + ((((size_t)b * 16 + h) << 11) + t0) * 64 + d;
#pragma unroll
          for (int r = 0; r < 4; ++r)
            qp[r * 64] = f2bf((acc[mf][nf][r] + bv) * 0.18033688011112042f);
        } else if (col < 2048) {
          const int c = col - 1024;
          const int h = c >> 6, d = c & 63;
          unsigned short* kp = ko + ((((size_t)b * 16 + h) << 11) + t0) * 64 + d;
#pragma unroll
          for (int r = 0; r < 4; ++r)
            kp[r * 64] = f2bf(acc[mf][nf][r] + bv);
        } else {
          const int c = col - 2048;
          const int h = c >> 6, d = c & 63;
          uint2 pk;
          pk.x = cvt_pk_bf16(acc[mf][nf][0] + bv, acc[mf][nf][1] + bv);
          pk.y = cvt_pk_bf16(acc[mf][nf][2] + bv, acc[mf][nf][3] + bv);
          *(uint2*)(vo + ((((size_t)b * 16 + h) << 6) + d) * 2048 + t0) = pk;
        }
      }
    }
  }
}

// ---------------- flash attention (causal), QBLK=64, dbuf, ZERO-EXCHANGE PV ----------------
// r10 pipeline (K/V dbuf, counted vmcnt(4), pair-balanced grid: 1024 identical
// 34-iter blocks, 4/CU) PLUS: the QK^T A-fragments are loaded from PERMUTED K rows
//   map(f, j) = 4*(f&1) + (j&3) + 8*(j>>2) + 32*(f>>1)
// so lane (g,q)'s S/P values land exactly on the PV B-fragment k-slice it needs:
// kv rows {8g..8g+7} (frags 0,1) and {32+8g..39+8g} (frags 2,3). P never touches
// LDS: the PV B-operand is built in-register with 8 cvt_pk. Removes 4 ds_write +
// 2 ds_read + the per-iter lgkmcnt(0) stall + 8KB LDS.
__global__ __launch_bounds__(256, 4)
void attn_fwd(const unsigned short* __restrict__ Qb,
              const unsigned short* __restrict__ Kb,
              const unsigned short* __restrict__ Vtb,
              unsigned short* __restrict__ Yb) {
  __shared__ __align__(16) char smem[32768];
  // buf0: K [0,8K) V [8K,16K); buf1: K [16K,24K) V [24K,32K)
  const int tid = threadIdx.x;
  const int ln = tid & 63;
  const int w = tid >> 6;
  const int g = ln >> 4, q = ln & 15;
  const int bh = blockIdx.x;
  const int pair = blockIdx.y;
  const size_t base = (size_t)bh * 2048 * 64;  // elements
  const int b = bh >> 4, h = bh & 15;
  // permuted A-row this lane supplies for fragment f: qrow + 4*(f&1) + 32*(f>>1)
  const int qrow = (q & 3) + 8 * (q >> 2);

  auto stage = [&](int j, int buf) {
    char* Kd = smem + buf * 16384;
    char* Vd = Kd + 8192;
    const int kv0 = j << 6;
    const char* Kg = (const char*)(Kb + base + (size_t)kv0 * 64);
    const char* Vg = (const char*)(Vtb + base) + kv0 * 2;
#pragma unroll
    for (int i = 0; i < 2; ++i) {
      const int chunk = i * 4 + w;                 // [0,8): 8 KB per tile
      const int o = chunk * 1024 + ln * 16;
      const int row = o >> 7;
      const int colb = (o & 127) ^ ((row & 7) << 4);
      gload_lds16(Kg + row * 128 + colb, Kd + chunk * 1024);
      gload_lds16(Vg + (size_t)row * 4096 + colb, Vd + chunk * 1024);
    }
  };

  auto run_qtile = [&](int qt) {     // qt in [0,32): 64 q-rows
    const int q0 = qt * 64;
    const int qw = q0 + w * 16;      // this wave's 16 q-rows

    bf16x8 qf[2];
#pragma unroll
    for (int kf = 0; kf < 2; ++kf)
      qf[kf] = ld16(Qb + base + (size_t)(qw + q) * 64 + kf * 32 + g * 8);
    WAIT_VMCNT(0);  // drains Q loads AND prior epilogue stores: counts stay exact

    float m_run = -INFINITY;
    float l_run = 0.f;
    f32x4 yt[4] = {};

    const int nkv = qt + 1;
    stage(0, 0);
    for (int j = 0; j < nkv; ++j) {
      if (j + 1 < nkv) {
        stage(j + 1, (j + 1) & 1);
        WAIT_VMCNT(4);
      } else {
        WAIT_VMCNT(0);
      }
      bar();

      const int kv0 = j << 6;
      const char* Ksm = smem + (j & 1) * 16384;
      const char* Vsm = Ksm + 8192;
      // ---- QK^T with permuted A-rows: st[f][r] = S[kv0 + 8g + 4(f&1) + 32(f>>1) + r][qw+q]
      f32x4 st[4] = {};
      __builtin_amdgcn_s_setprio(1);
#pragma unroll
      for (int f = 0; f < 4; ++f) {
        const int row = qrow + 4 * (f & 1) + 32 * (f >> 1);  // permuted K row
        const int swz = (row & 7) << 4;
        const bf16x8 a0 = ld16(Ksm + ((row * 128 + g * 16) ^ swz));
        const bf16x8 a1 = ld16(Ksm + ((row * 128 + 64 + g * 16) ^ swz));
        st[f] = mfma16(a0, qf[0], st[f]);
        st[f] = mfma16(a1, qf[1], st[f]);
      }
      __builtin_amdgcn_s_setprio(0);
      if (kv0 + 63 > qw) {  // diagonal tile: causal mask (permuted kv indexing)
#pragma unroll
        for (int f = 0; f < 4; ++f) {
          const int kvb = kv0 + 8 * g + 4 * (f & 1) + 32 * (f >> 1);
#pragma unroll
          for (int r = 0; r < 4; ++r)
            if (kvb + r > qw + q) st[f][r] = -INFINITY;
        }
      }
      // ---- online softmax (base-2 domain; Q pre-scaled log2e/8), all in-lane ----
      {
        float vmax = -INFINITY;
#pragma unroll
        for (int f = 0; f < 4; ++f) {
          const f32x4 v = st[f];
          vmax = fmaxf(fmaxf(vmax, fmaxf(v[0], v[1])), fmaxf(v[2], v[3]));
        }
        vmax = fmaxf(vmax, __shfl_xor(vmax, 16));
        vmax = fmaxf(vmax, __shfl_xor(vmax, 32));
        const float mo = m_run;
        if (__any(vmax > mo)) {  // exact skip: if no lane grows, corr == 1 exactly
          const float mn = fmaxf(mo, vmax);
          const float corr = exp2_fast(mo - mn);
          m_run = mn;
          l_run *= corr;
#pragma unroll
          for (int mfd = 0; mfd < 4; ++mfd) yt[mfd] *= corr;
        }
        const float mcur = m_run;
        float ls = 0.f;
#pragma unroll
        for (int f = 0; f < 4; ++f) {
#pragma unroll
          for (int r = 0; r < 4; ++r) {
            st[f][r] = exp2_fast(st[f][r] - mcur);
            ls += st[f][r];
          }
        }
        ls += __shfl_xor(ls, 16);
        ls += __shfl_xor(ls, 32);
        l_run += ls;
      }
      // ---- PV B-operand built IN-REGISTER (zero exchange) ----
      union { uint4 u; bf16x8 b; } pb0, pb1;
      pb0.u.x = cvt_pk_bf16(st[0][0], st[0][1]);
      pb0.u.y = cvt_pk_bf16(st[0][2], st[0][3]);
      pb0.u.z = cvt_pk_bf16(st[1][0], st[1][1]);
      pb0.u.w = cvt_pk_bf16(st[1][2], st[1][3]);
      pb1.u.x = cvt_pk_bf16(st[2][0], st[2][1]);
      pb1.u.y = cvt_pk_bf16(st[2][2], st[2][3]);
      pb1.u.z = cvt_pk_bf16(st[3][0], st[3][1]);
      pb1.u.w = cvt_pk_bf16(st[3][2], st[3][3]);
      // PV: Y^T[d][q] += Vt * P^T
      __builtin_amdgcn_s_setprio(1);
#pragma unroll
      for (int mfd = 0; mfd < 4; ++mfd) {
        const int vrow = mfd * 16 + q;
        const int swz = (vrow & 7) << 4;
        const bf16x8 v0 = ld16(Vsm + ((vrow * 128 + g * 16) ^ swz));
        const bf16x8 v1 = ld16(Vsm + ((vrow * 128 + 64 + g * 16) ^ swz));
        yt[mfd] = mfma16(v0, pb0.b, yt[mfd]);
        yt[mfd] = mfma16(v1, pb1.b, yt[mfd]);
      }
      __builtin_amdgcn_s_setprio(0);
      bar();  // all waves done reading K/V before next stage overwrites
    }

    const float inv = 1.f / l_run;
    const int qr = qw + q;
    unsigned short* yp = Yb + (size_t)(b * 2048 + qr) * 1024 + h * 64;
#pragma unroll
    for (int mfd = 0; mfd < 4; ++mfd) {
      uint2 o2;
      o2.x = cvt_pk_bf16(yt[mfd][0] * inv, yt[mfd][1] * inv);
      o2.y = cvt_pk_bf16(yt[mfd][2] * inv, yt[mfd][3] * inv);
      *(uint2*)(yp + mfd * 16 + g * 4) = o2;
    }
  };

  run_qtile(31 - pair);  // heavy q-tile first: 32-pair iters
  run_qtile(pair);       // light q-tile: pair+2... total = 34 for every block
}

extern "C" void kernel_launch(void* const* d_in, const int* in_sizes, int n_in,
                              void* d_out, int out_size, void* d_ws, size_t ws_size,
                              hipStream_t stream) {
  const float* x      = (const float*)d_in[0];
  const float* w_qkv  = (const float*)d_in[1];
  const float* b_qkv  = (const float*)d_in[2];
  const float* w_proj = (const float*)d_in[3];
  const float* b_proj = (const float*)d_in[4];
  float* out = (float*)d_out;
  char* ws = (char*)d_ws;

  unsigned short* xb  = (unsigned short*)(ws);                       // 16 MB x bf16
  unsigned short* wqb = (unsigned short*)(ws + (size_t)(16 << 20));  //  6 MB w_qkv bf16
  unsigned short* wpb = (unsigned short*)(ws + (size_t)(22 << 20));  //  2 MB w_proj bf16
  unsigned short* Qb  = (unsigned short*)(ws + (size_t)(24 << 20));  // 16 MB Q (pre-scaled log2e/8)
  unsigned short* Kb  = (unsigned short*)(ws + (size_t)(40 << 20));  // 16 MB K [bh][t][d]
  unsigned short* Vtb = (unsigned short*)(ws + (size_t)(56 << 20));  // 16 MB V^T [bh][d][t]
  unsigned short* Yb  = (unsigned short*)(ws + (size_t)(72 << 20));  // 16 MB attn out bf16

  cvt_all<<<12288, 256, 0, stream>>>(x, w_qkv, w_proj, xb, wqb, wpb);
  gemm_bt<3072, 1><<<dim3(64, 24), 256, 0, stream>>>(xb, wqb, b_qkv, nullptr, Qb, Kb, Vtb);
  attn_fwd<<<dim3(64, 16), 256, 0, stream>>>(Qb, Kb, Vtb, Yb);
  gemm_bt<1024, 0><<<dim3(64, 8), 256, 0, stream>>>(Yb, wpb, b_proj, out, nullptr, nullptr, nullptr);
}

// Round 12
// 163.957 us; speedup vs baseline: 1.4042x; 1.0099x over previous
//
#include <hip/hip_runtime.h>

typedef __bf16 bf16x8 __attribute__((ext_vector_type(8)));
typedef float f32x4 __attribute__((ext_vector_type(4)));

#define DI __device__ __forceinline__

// Pinned counted waitcnt: memory clobber + sched_barrier so global_load_lds
// intrinsics cannot be reordered around it (rule #18).
#define WAIT_VMCNT(N)                                        \
  do {                                                       \
    __builtin_amdgcn_sched_barrier(0);                       \
    asm volatile("s_waitcnt vmcnt(" #N ")" ::: "memory");    \
    __builtin_amdgcn_sched_barrier(0);                       \
  } while (0)

DI unsigned short f2bf(float f) {
  unsigned int u = __float_as_uint(f);
  u += 0x7FFFu + ((u >> 16) & 1u);
  return (unsigned short)(u >> 16);
}

DI unsigned cvt_pk_bf16(float a, float b) {  // lo=bf16(a), hi=bf16(b)
  unsigned r;
  asm("v_cvt_pk_bf16_f32 %0, %1, %2" : "=v"(r) : "v"(a), "v"(b));
  return r;
}

DI float exp2_fast(float x) {  // raw v_exp_f32 (2^x); exp2(-inf)=0
  float r;
  asm("v_exp_f32 %0, %1" : "=v"(r) : "v"(x));
  return r;
}

DI void fence() { asm volatile("" ::: "memory"); }
DI void bar() { fence(); __builtin_amdgcn_s_barrier(); fence(); }

DI bf16x8 ld16(const void* p) {
  union { uint4 u; bf16x8 b; } c;
  c.u = *reinterpret_cast<const uint4*>(p);
  return c.b;
}

DI f32x4 mfma16(bf16x8 a, bf16x8 b, f32x4 c) {
  return __builtin_amdgcn_mfma_f32_16x16x32_bf16(a, b, c, 0, 0, 0);
}

DI void gload_lds16(const void* g, void* l) {
  __builtin_amdgcn_global_load_lds(
      (const __attribute__((address_space(1))) unsigned int*)g,
      (__attribute__((address_space(3))) unsigned int*)l, 16, 0, 0);
}

// ---------------- fused fp32 -> bf16 convert (x, w_qkv, w_proj) ----------------
__global__ void cvt_all(const float* __restrict__ x, const float* __restrict__ wq,
                        const float* __restrict__ wp,
                        unsigned short* __restrict__ xb, unsigned short* __restrict__ wqb,
                        unsigned short* __restrict__ wpb) {
  int i = blockIdx.x * blockDim.x + threadIdx.x;  // float4 index
  const float* s;
  unsigned short* d;
  int off;
  if (i < 2097152) { s = x; d = xb; off = i; }
  else if (i < 2097152 + 786432) { s = wq; d = wqb; off = i - 2097152; }
  else { s = wp; d = wpb; off = i - (2097152 + 786432); }
  float4 v = reinterpret_cast<const float4*>(s)[off];
  uint2 o;
  o.x = cvt_pk_bf16(v.x, v.y);
  o.y = cvt_pk_bf16(v.z, v.w);
  reinterpret_cast<uint2*>(d)[off] = o;
}

// ---------------- GEMM: C[M,N] = A[M,K] * W[N,K]^T + bias ----------------
// PROVEN round-1 structure: 128x128 tile, BK=64, 4 waves (2x2), single-buffered
// LDS (A 16K | B 16K), full drain + barrier per K-step. XOR bank-swizzle on the
// pre-swizzled global source + again on ds_read (involution).
// MODE 0: out = fp32 row-major [M][N] (+bias)
// MODE 1: qkv scatter -> Q (scaled log2e/8), K head-major; V transposed [bh][d][t]
//         (V^T stores packed as uint2: in-lane r's are 4 consecutive t)
template <int N, int MODE>
__global__ __launch_bounds__(256)
void gemm_bt(const unsigned short* __restrict__ A,
             const unsigned short* __restrict__ W,
             const float* __restrict__ bias,
             float* __restrict__ out,
             unsigned short* __restrict__ qo,
             unsigned short* __restrict__ ko,
             unsigned short* __restrict__ vo) {
  constexpr int K = 1024;
  __shared__ __align__(16) char smem[32768];  // A tile 16K | B tile 16K
  char* Asm = smem;
  char* Bsm = smem + 16384;
  const int tid = threadIdx.x;
  const int ln = tid & 63;
  const int w  = tid >> 6;
  const int wm = w >> 1, wn = w & 1;
  const int g = ln >> 4, q = ln & 15;
  const int m0 = blockIdx.x * 128;
  const int n0 = blockIdx.y * 128;

  f32x4 acc[4][4] = {};

  for (int kt = 0; kt < K / 64; ++kt) {
    if (kt) bar();  // previous compute's LDS reads done before overwrite
#pragma unroll
    for (int i = 0; i < 4; ++i) {
      const int chunk = i * 4 + w;                 // [0,16): full 16 KB tile
      const int o = chunk * 1024 + ln * 16;
      const int row = o >> 7;
      const int colb = (o & 127) ^ ((row & 7) << 4);
      gload_lds16((const char*)A + ((size_t)(m0 + row) * K + kt * 64) * 2 + colb,
                  Asm + chunk * 1024);
      gload_lds16((const char*)W + ((size_t)(n0 + row) * K + kt * 64) * 2 + colb,
                  Bsm + chunk * 1024);
    }
    WAIT_VMCNT(0);
    bar();
#pragma unroll
    for (int ks = 0; ks < 2; ++ks) {
      bf16x8 av[4], bv[4];
#pragma unroll
      for (int mf = 0; mf < 4; ++mf) {
        const int row = wm * 64 + mf * 16 + q;
        av[mf] = ld16(Asm + ((row * 128 + ks * 64 + g * 16) ^ ((row & 7) << 4)));
      }
#pragma unroll
      for (int nf = 0; nf < 4; ++nf) {
        const int row = wn * 64 + nf * 16 + q;
        bv[nf] = ld16(Bsm + ((row * 128 + ks * 64 + g * 16) ^ ((row & 7) << 4)));
      }
#pragma unroll
      for (int mf = 0; mf < 4; ++mf)
#pragma unroll
        for (int nf = 0; nf < 4; ++nf)
          acc[mf][nf] = mfma16(av[mf], bv[nf], acc[mf][nf]);
    }
  }

#pragma unroll
  for (int nf = 0; nf < 4; ++nf) {
    const int col = n0 + wn * 64 + nf * 16 + q;
    const float bv = bias[col];
#pragma unroll
    for (int mf = 0; mf < 4; ++mf) {
      const int rbase = m0 + wm * 64 + mf * 16 + g * 4;
      if constexpr (MODE == 0) {
#pragma unroll
        for (int r = 0; r < 4; ++r)
          out[(size_t)(rbase + r) * N + col] = acc[mf][nf][r] + bv;
      } else {
        const int b = rbase >> 11, t0 = rbase & 2047;  // 4 consecutive t, same b
        if (col < 1024) {
          const int h = col >> 6, d = col & 63;
          unsigned short* qp = qo + ((((size_t)b * 16 + h) << 11) + t0) * 64 + d;
#pragma unroll
          for (int r = 0; r < 4; ++r)
            qp[r * 64] = f2bf((acc[mf][nf][r] + bv) * 0.18033688011112042f);
        } else if (col < 2048) {
          const int c = col - 1024;
          const int h = c >> 6, d = c & 63;
          unsigned short* kp = ko + ((((size_t)b * 16 + h) << 11) + t0) * 64 + d;
#pragma unroll
          for (int r = 0; r < 4; ++r)
            kp[r * 64] = f2bf(acc[mf][nf][r] + bv);
        } else {
          const int c = col - 2048;
          const int h = c >> 6, d = c & 63;
          uint2 pk;
          pk.x = cvt_pk_bf16(acc[mf][nf][0] + bv, acc[mf][nf][1] + bv);
          pk.y = cvt_pk_bf16(acc[mf][nf][2] + bv, acc[mf][nf][3] + bv);
          *(uint2*)(vo + ((((size_t)b * 16 + h) << 6) + d) * 2048 + t0) = pk;
        }
      }
    }
  }
}

// attention swizzle: slot bits 0-1 from row bits 0-1, slot bit 2 from row BIT 3.
// Matches the permuted K-read (row = (q&3)+4(f&1)+8(q>>2)+32(f>>1) -> s varies in
// all 3 bits across the wave) AND the V-read (vrow = mfd*16+q) -> both patterns
// spread 64 lanes uniformly over all 8 16B slots = conflict-free ds_read_b128.
DI int asb(int row) { return ((row & 3) | (((row >> 3) & 1) << 2)) << 4; }

// ---------------- flash attention (causal), QBLK=64, dbuf, ZERO-EXCHANGE PV ----------------
// r11 structure (K/V dbuf, counted vmcnt(4), pair-balanced 1024x34-iter grid,
// permuted-A-row QK^T so P stays in-lane, in-register PV B-operand) with the
// conflict-free asb() swizzle replacing (row&7)<<4.
__global__ __launch_bounds__(256, 4)
void attn_fwd(const unsigned short* __restrict__ Qb,
              const unsigned short* __restrict__ Kb,
              const unsigned short* __restrict__ Vtb,
              unsigned short* __restrict__ Yb) {
  __shared__ __align__(16) char smem[32768];
  // buf0: K [0,8K) V [8K,16K); buf1: K [16K,24K) V [24K,32K)
  const int tid = threadIdx.x;
  const int ln = tid & 63;
  const int w = tid >> 6;
  const int g = ln >> 4, q = ln & 15;
  const int bh = blockIdx.x;
  const int pair = blockIdx.y;
  const size_t base = (size_t)bh * 2048 * 64;  // elements
  const int b = bh >> 4, h = bh & 15;
  // permuted A-row this lane supplies for fragment f: qrow + 4*(f&1) + 32*(f>>1)
  const int qrow = (q & 3) + 8 * (q >> 2);

  auto stage = [&](int j, int buf) {
    char* Kd = smem + buf * 16384;
    char* Vd = Kd + 8192;
    const int kv0 = j << 6;
    const char* Kg = (const char*)(Kb + base + (size_t)kv0 * 64);
    const char* Vg = (const char*)(Vtb + base) + kv0 * 2;
#pragma unroll
    for (int i = 0; i < 2; ++i) {
      const int chunk = i * 4 + w;                 // [0,8): 8 KB per tile
      const int o = chunk * 1024 + ln * 16;
      const int row = o >> 7;
      const int colb = (o & 127) ^ asb(row);
      gload_lds16(Kg + row * 128 + colb, Kd + chunk * 1024);
      gload_lds16(Vg + (size_t)row * 4096 + colb, Vd + chunk * 1024);
    }
  };

  auto run_qtile = [&](int qt) {     // qt in [0,32): 64 q-rows
    const int q0 = qt * 64;
    const int qw = q0 + w * 16;      // this wave's 16 q-rows

    bf16x8 qf[2];
#pragma unroll
    for (int kf = 0; kf < 2; ++kf)
      qf[kf] = ld16(Qb + base + (size_t)(qw + q) * 64 + kf * 32 + g * 8);
    WAIT_VMCNT(0);  // drains Q loads AND prior epilogue stores: counts stay exact

    float m_run = -INFINITY;
    float l_run = 0.f;
    f32x4 yt[4] = {};

    const int nkv = qt + 1;
    stage(0, 0);
    for (int j = 0; j < nkv; ++j) {
      if (j + 1 < nkv) {
        stage(j + 1, (j + 1) & 1);
        WAIT_VMCNT(4);
      } else {
        WAIT_VMCNT(0);
      }
      bar();

      const int kv0 = j << 6;
      const char* Ksm = smem + (j & 1) * 16384;
      const char* Vsm = Ksm + 8192;
      // ---- QK^T with permuted A-rows: st[f][r] = S[kv0 + 8g + 4(f&1) + 32(f>>1) + r][qw+q]
      f32x4 st[4] = {};
      __builtin_amdgcn_s_setprio(1);
#pragma unroll
      for (int f = 0; f < 4; ++f) {
        const int row = qrow + 4 * (f & 1) + 32 * (f >> 1);  // permuted K row
        const int swz = asb(row);
        const bf16x8 a0 = ld16(Ksm + ((row * 128 + g * 16) ^ swz));
        const bf16x8 a1 = ld16(Ksm + ((row * 128 + 64 + g * 16) ^ swz));
        st[f] = mfma16(a0, qf[0], st[f]);
        st[f] = mfma16(a1, qf[1], st[f]);
      }
      __builtin_amdgcn_s_setprio(0);
      if (kv0 + 63 > qw) {  // diagonal tile: causal mask (permuted kv indexing)
#pragma unroll
        for (int f = 0; f < 4; ++f) {
          const int kvb = kv0 + 8 * g + 4 * (f & 1) + 32 * (f >> 1);
#pragma unroll
          for (int r = 0; r < 4; ++r)
            if (kvb + r > qw + q) st[f][r] = -INFINITY;
        }
      }
      // ---- online softmax (base-2 domain; Q pre-scaled log2e/8), all in-lane ----
      {
        float vmax = -INFINITY;
#pragma unroll
        for (int f = 0; f < 4; ++f) {
          const f32x4 v = st[f];
          vmax = fmaxf(fmaxf(vmax, fmaxf(v[0], v[1])), fmaxf(v[2], v[3]));
        }
        vmax = fmaxf(vmax, __shfl_xor(vmax, 16));
        vmax = fmaxf(vmax, __shfl_xor(vmax, 32));
        const float mo = m_run;
        if (__any(vmax > mo)) {  // exact skip: if no lane grows, corr == 1 exactly
          const float mn = fmaxf(mo, vmax);
          const float corr = exp2_fast(mo - mn);
          m_run = mn;
          l_run *= corr;
#pragma unroll
          for (int mfd = 0; mfd < 4; ++mfd) yt[mfd] *= corr;
        }
        const float mcur = m_run;
        float ls = 0.f;
#pragma unroll
        for (int f = 0; f < 4; ++f) {
#pragma unroll
          for (int r = 0; r < 4; ++r) {
            st[f][r] = exp2_fast(st[f][r] - mcur);
            ls += st[f][r];
          }
        }
        ls += __shfl_xor(ls, 16);
        ls += __shfl_xor(ls, 32);
        l_run += ls;
      }
      // ---- PV B-operand built IN-REGISTER (zero exchange) ----
      union { uint4 u; bf16x8 b; } pb0, pb1;
      pb0.u.x = cvt_pk_bf16(st[0][0], st[0][1]);
      pb0.u.y = cvt_pk_bf16(st[0][2], st[0][3]);
      pb0.u.z = cvt_pk_bf16(st[1][0], st[1][1]);
      pb0.u.w = cvt_pk_bf16(st[1][2], st[1][3]);
      pb1.u.x = cvt_pk_bf16(st[2][0], st[2][1]);
      pb1.u.y = cvt_pk_bf16(st[2][2], st[2][3]);
      pb1.u.z = cvt_pk_bf16(st[3][0], st[3][1]);
      pb1.u.w = cvt_pk_bf16(st[3][2], st[3][3]);
      // PV: Y^T[d][q] += Vt * P^T
      __builtin_amdgcn_s_setprio(1);
#pragma unroll
      for (int mfd = 0; mfd < 4; ++mfd) {
        const int vrow = mfd * 16 + q;
        const int swz = asb(vrow);
        const bf16x8 v0 = ld16(Vsm + ((vrow * 128 + g * 16) ^ swz));
        const bf16x8 v1 = ld16(Vsm + ((vrow * 128 + 64 + g * 16) ^ swz));
        yt[mfd] = mfma16(v0, pb0.b, yt[mfd]);
        yt[mfd] = mfma16(v1, pb1.b, yt[mfd]);
      }
      __builtin_amdgcn_s_setprio(0);
      bar();  // all waves done reading K/V before next stage overwrites
    }

    const float inv = 1.f / l_run;
    const int qr = qw + q;
    unsigned short* yp = Yb + (size_t)(b * 2048 + qr) * 1024 + h * 64;
#pragma unroll
    for (int mfd = 0; mfd < 4; ++mfd) {
      uint2 o2;
      o2.x = cvt_pk_bf16(yt[mfd][0] * inv, yt[mfd][1] * inv);
      o2.y = cvt_pk_bf16(yt[mfd][2] * inv, yt[mfd][3] * inv);
      *(uint2*)(yp + mfd * 16 + g * 4) = o2;
    }
  };

  run_qtile(31 - pair);  // heavy q-tile first: 32-pair iters
  run_qtile(pair);       // light q-tile: pair+2... total = 34 for every block
}

extern "C" void kernel_launch(void* const* d_in, const int* in_sizes, int n_in,
                              void* d_out, int out_size, void* d_ws, size_t ws_size,
                              hipStream_t stream) {
  const float* x      = (const float*)d_in[0];
  const float* w_qkv  = (const float*)d_in[1];
  const float* b_qkv  = (const float*)d_in[2];
  const float* w_proj = (const float*)d_in[3];
  const float* b_proj = (const float*)d_in[4];
  float* out = (float*)d_out;
  char* ws = (char*)d_ws;

  unsigned short* xb  = (unsigned short*)(ws);                       // 16 MB x bf16
  unsigned short* wqb = (unsigned short*)(ws + (size_t)(16 << 20));  //  6 MB w_qkv bf16
  unsigned short* wpb = (unsigned short*)(ws + (size_t)(22 << 20));  //  2 MB w_proj bf16
  unsigned short* Qb  = (unsigned short*)(ws + (size_t)(24 << 20));  // 16 MB Q (pre-scaled log2e/8)
  unsigned short* Kb  = (unsigned short*)(ws + (size_t)(40 << 20));  // 16 MB K [bh][t][d]
  unsigned short* Vtb = (unsigned short*)(ws + (size_t)(56 << 20));  // 16 MB V^T [bh][d][t]
  unsigned short* Yb  = (unsigned short*)(ws + (size_t)(72 << 20));  // 16 MB attn out bf16

  cvt_all<<<12288, 256, 0, stream>>>(x, w_qkv, w_proj, xb, wqb, wpb);
  gemm_bt<3072, 1><<<dim3(64, 24), 256, 0, stream>>>(xb, wqb, b_qkv, nullptr, Qb, Kb, Vtb);
  attn_fwd<<<dim3(64, 16), 256, 0, stream>>>(Qb, Kb, Vtb, Yb);
  gemm_bt<1024, 0><<<dim3(64, 8), 256, 0, stream>>>(Yb, wpb, b_proj, out, nullptr, nullptr, nullptr);
}

// Round 13
// 160.518 us; speedup vs baseline: 1.4343x; 1.0214x over previous
//
#include <hip/hip_runtime.h>

typedef __bf16 bf16x8 __attribute__((ext_vector_type(8)));
typedef float f32x4 __attribute__((ext_vector_type(4)));

#define DI __device__ __forceinline__

// Pinned counted waitcnt: memory clobber + sched_barrier so global_load_lds
// intrinsics cannot be reordered around it (rule #18).
#define WAIT_VMCNT(N)                                        \
  do {                                                       \
    __builtin_amdgcn_sched_barrier(0);                       \
    asm volatile("s_waitcnt vmcnt(" #N ")" ::: "memory");    \
    __builtin_amdgcn_sched_barrier(0);                       \
  } while (0)

DI unsigned short f2bf(float f) {
  unsigned int u = __float_as_uint(f);
  u += 0x7FFFu + ((u >> 16) & 1u);
  return (unsigned short)(u >> 16);
}

DI unsigned cvt_pk_bf16(float a, float b) {  // lo=bf16(a), hi=bf16(b)
  unsigned r;
  asm("v_cvt_pk_bf16_f32 %0, %1, %2" : "=v"(r) : "v"(a), "v"(b));
  return r;
}

DI float exp2_fast(float x) {  // raw v_exp_f32 (2^x); exp2(-inf)=0
  float r;
  asm("v_exp_f32 %0, %1" : "=v"(r) : "v"(x));
  return r;
}

DI void fence() { asm volatile("" ::: "memory"); }
DI void bar() { fence(); __builtin_amdgcn_s_barrier(); fence(); }

DI bf16x8 ld16(const void* p) {
  union { uint4 u; bf16x8 b; } c;
  c.u = *reinterpret_cast<const uint4*>(p);
  return c.b;
}

DI f32x4 mfma16(bf16x8 a, bf16x8 b, f32x4 c) {
  return __builtin_amdgcn_mfma_f32_16x16x32_bf16(a, b, c, 0, 0, 0);
}

DI void gload_lds16(const void* g, void* l) {
  __builtin_amdgcn_global_load_lds(
      (const __attribute__((address_space(1))) unsigned int*)g,
      (__attribute__((address_space(3))) unsigned int*)l, 16, 0, 0);
}

// ---------------- fused fp32 -> bf16 convert (x, w_qkv, w_proj) ----------------
__global__ void cvt_all(const float* __restrict__ x, const float* __restrict__ wq,
                        const float* __restrict__ wp,
                        unsigned short* __restrict__ xb, unsigned short* __restrict__ wqb,
                        unsigned short* __restrict__ wpb) {
  int i = blockIdx.x * blockDim.x + threadIdx.x;  // float4 index
  const float* s;
  unsigned short* d;
  int off;
  if (i < 2097152) { s = x; d = xb; off = i; }
  else if (i < 2097152 + 786432) { s = wq; d = wqb; off = i - 2097152; }
  else { s = wp; d = wpb; off = i - (2097152 + 786432); }
  float4 v = reinterpret_cast<const float4*>(s)[off];
  uint2 o;
  o.x = cvt_pk_bf16(v.x, v.y);
  o.y = cvt_pk_bf16(v.z, v.w);
  reinterpret_cast<uint2*>(d)[off] = o;
}

// ---------------- GEMM: C[M,N] = A[M,K] * W[N,K]^T + bias ----------------
// PROVEN round-1 structure: 128x128 tile, BK=64, 4 waves (2x2), single-buffered
// LDS (A 16K | B 16K), full drain + barrier per K-step. XOR bank-swizzle on the
// pre-swizzled global source + again on ds_read (involution).
// MODE 0: out = fp32 row-major [M][N] (+bias)
// MODE 1: qkv scatter -> Q (scaled log2e/8), K head-major; V transposed [bh][d][t]
//         (V^T stores packed as uint2: in-lane r's are 4 consecutive t)
template <int N, int MODE>
__global__ __launch_bounds__(256)
void gemm_bt(const unsigned short* __restrict__ A,
             const unsigned short* __restrict__ W,
             const float* __restrict__ bias,
             float* __restrict__ out,
             unsigned short* __restrict__ qo,
             unsigned short* __restrict__ ko,
             unsigned short* __restrict__ vo) {
  constexpr int K = 1024;
  __shared__ __align__(16) char smem[32768];  // A tile 16K | B tile 16K
  char* Asm = smem;
  char* Bsm = smem + 16384;
  const int tid = threadIdx.x;
  const int ln = tid & 63;
  const int w  = tid >> 6;
  const int wm = w >> 1, wn = w & 1;
  const int g = ln >> 4, q = ln & 15;
  const int m0 = blockIdx.x * 128;
  const int n0 = blockIdx.y * 128;

  f32x4 acc[4][4] = {};

  for (int kt = 0; kt < K / 64; ++kt) {
    if (kt) bar();  // previous compute's LDS reads done before overwrite
#pragma unroll
    for (int i = 0; i < 4; ++i) {
      const int chunk = i * 4 + w;                 // [0,16): full 16 KB tile
      const int o = chunk * 1024 + ln * 16;
      const int row = o >> 7;
      const int colb = (o & 127) ^ ((row & 7) << 4);
      gload_lds16((const char*)A + ((size_t)(m0 + row) * K + kt * 64) * 2 + colb,
                  Asm + chunk * 1024);
      gload_lds16((const char*)W + ((size_t)(n0 + row) * K + kt * 64) * 2 + colb,
                  Bsm + chunk * 1024);
    }
    WAIT_VMCNT(0);
    bar();
#pragma unroll
    for (int ks = 0; ks < 2; ++ks) {
      bf16x8 av[4], bv[4];
#pragma unroll
      for (int mf = 0; mf < 4; ++mf) {
        const int row = wm * 64 + mf * 16 + q;
        av[mf] = ld16(Asm + ((row * 128 + ks * 64 + g * 16) ^ ((row & 7) << 4)));
      }
#pragma unroll
      for (int nf = 0; nf < 4; ++nf) {
        const int row = wn * 64 + nf * 16 + q;
        bv[nf] = ld16(Bsm + ((row * 128 + ks * 64 + g * 16) ^ ((row & 7) << 4)));
      }
#pragma unroll
      for (int mf = 0; mf < 4; ++mf)
#pragma unroll
        for (int nf = 0; nf < 4; ++nf)
          acc[mf][nf] = mfma16(av[mf], bv[nf], acc[mf][nf]);
    }
  }

#pragma unroll
  for (int nf = 0; nf < 4; ++nf) {
    const int col = n0 + wn * 64 + nf * 16 + q;
    const float bv = bias[col];
#pragma unroll
    for (int mf = 0; mf < 4; ++mf) {
      const int rbase = m0 + wm * 64 + mf * 16 + g * 4;
      if constexpr (MODE == 0) {
#pragma unroll
        for (int r = 0; r < 4; ++r)
          out[(size_t)(rbase + r) * N + col] = acc[mf][nf][r] + bv;
      } else {
        const int b = rbase >> 11, t0 = rbase & 2047;  // 4 consecutive t, same b
        if (col < 1024) {
          const int h = col >> 6, d = col & 63;
          unsigned short* qp = qo + ((((size_t)b * 16 + h) << 11) + t0) * 64 + d;
#pragma unroll
          for (int r = 0; r < 4; ++r)
            qp[r * 64] = f2bf((acc[mf][nf][r] + bv) * 0.18033688011112042f);
        } else if (col < 2048) {
          const int c = col - 1024;
          const int h = c >> 6, d = c & 63;
          unsigned short* kp = ko + ((((size_t)b * 16 + h) << 11) + t0) * 64 + d;
#pragma unroll
          for (int r = 0; r < 4; ++r)
            kp[r * 64] = f2bf(acc[mf][nf][r] + bv);
        } else {
          const int c = col - 2048;
          const int h = c >> 6, d = c & 63;
          uint2 pk;
          pk.x = cvt_pk_bf16(acc[mf][nf][0] + bv, acc[mf][nf][1] + bv);
          pk.y = cvt_pk_bf16(acc[mf][nf][2] + bv, acc[mf][nf][3] + bv);
          *(uint2*)(vo + ((((size_t)b * 16 + h) << 6) + d) * 2048 + t0) = pk;
        }
      }
    }
  }
}

// attention swizzle: slot bits 0-1 from row bits 0-1, slot bit 2 from row BIT 3.
// Conflict-free for both the permuted K-read and the V-read (r12, measured 0).
DI int asb(int row) { return ((row & 3) | (((row >> 3) & 1) << 2)) << 4; }

// ---------------- flash attention (causal), MERGED-PAIR, ZERO-EXCHANGE PV ----------------
// The kv-tile stream of q-tile p is a PREFIX of q-tile 31-p's stream. Each block
// owns the pair {31-p, p} and runs ONE merged kv-loop of (32-p) staged tiles:
// hi tile consumes every tile, lo tile consumes tiles j<=p. Compute = 33 units
// per block (constant); staging iterations and barriers drop ~26% on average
// vs the sequential pair (r12: 33 stages/66 barriers -> avg 24.5/49).
// Per-tile compute is byte-identical to r12: permuted-A-row QK^T (P stays in-lane),
// in-register PV B-operand, asb() conflict-free swizzle, K/V dbuf + counted vmcnt(4).
__global__ __launch_bounds__(256, 4)
void attn_fwd(const unsigned short* __restrict__ Qb,
              const unsigned short* __restrict__ Kb,
              const unsigned short* __restrict__ Vtb,
              unsigned short* __restrict__ Yb) {
  __shared__ __align__(16) char smem[32768];
  // buf0: K [0,8K) V [8K,16K); buf1: K [16K,24K) V [24K,32K)
  const int tid = threadIdx.x;
  const int ln = tid & 63;
  const int w = tid >> 6;
  const int g = ln >> 4, q = ln & 15;
  const int bh = blockIdx.x;
  const int pair = blockIdx.y;        // p = 0 dispatches first: longest staging loop (LPT)
  const size_t base = (size_t)bh * 2048 * 64;  // elements
  const int b = bh >> 4, h = bh & 15;
  // permuted A-row this lane supplies for fragment f: qrow + 4*(f&1) + 32*(f>>1)
  const int qrow = (q & 3) + 8 * (q >> 2);

  auto stage = [&](int j, int buf) {
    char* Kd = smem + buf * 16384;
    char* Vd = Kd + 8192;
    const int kv0 = j << 6;
    const char* Kg = (const char*)(Kb + base + (size_t)kv0 * 64);
    const char* Vg = (const char*)(Vtb + base) + kv0 * 2;
#pragma unroll
    for (int i = 0; i < 2; ++i) {
      const int chunk = i * 4 + w;                 // [0,8): 8 KB per tile
      const int o = chunk * 1024 + ln * 16;
      const int row = o >> 7;
      const int colb = (o & 127) ^ asb(row);
      gload_lds16(Kg + row * 128 + colb, Kd + chunk * 1024);
      gload_lds16(Vg + (size_t)row * 4096 + colb, Vd + chunk * 1024);
    }
  };

  // one kv-tile of online-softmax attention for one q-sub-tile (16 rows/wave)
  auto tile_step = [&](const bf16x8* qf, float& m_run, float& l_run, f32x4* yt,
                       int qw, int kv0, const char* Ksm, const char* Vsm) {
    // ---- QK^T with permuted A-rows: st[f][r] = S[kv0 + 8g + 4(f&1) + 32(f>>1) + r][qw+q]
    f32x4 st[4] = {};
    __builtin_amdgcn_s_setprio(1);
#pragma unroll
    for (int f = 0; f < 4; ++f) {
      const int row = qrow + 4 * (f & 1) + 32 * (f >> 1);  // permuted K row
      const int swz = asb(row);
      const bf16x8 a0 = ld16(Ksm + ((row * 128 + g * 16) ^ swz));
      const bf16x8 a1 = ld16(Ksm + ((row * 128 + 64 + g * 16) ^ swz));
      st[f] = mfma16(a0, qf[0], st[f]);
      st[f] = mfma16(a1, qf[1], st[f]);
    }
    __builtin_amdgcn_s_setprio(0);
    if (kv0 + 63 > qw) {  // diagonal tile: causal mask (permuted kv indexing)
#pragma unroll
      for (int f = 0; f < 4; ++f) {
        const int kvb = kv0 + 8 * g + 4 * (f & 1) + 32 * (f >> 1);
#pragma unroll
        for (int r = 0; r < 4; ++r)
          if (kvb + r > qw + q) st[f][r] = -INFINITY;
      }
    }
    // ---- online softmax (base-2 domain; Q pre-scaled log2e/8), all in-lane ----
    {
      float vmax = -INFINITY;
#pragma unroll
      for (int f = 0; f < 4; ++f) {
        const f32x4 v = st[f];
        vmax = fmaxf(fmaxf(vmax, fmaxf(v[0], v[1])), fmaxf(v[2], v[3]));
      }
      vmax = fmaxf(vmax, __shfl_xor(vmax, 16));
      vmax = fmaxf(vmax, __shfl_xor(vmax, 32));
      const float mo = m_run;
      if (__any(vmax > mo)) {  // exact skip: if no lane grows, corr == 1 exactly
        const float mn = fmaxf(mo, vmax);
        const float corr = exp2_fast(mo - mn);
        m_run = mn;
        l_run *= corr;
#pragma unroll
        for (int mfd = 0; mfd < 4; ++mfd) yt[mfd] *= corr;
      }
      const float mcur = m_run;
      float ls = 0.f;
#pragma unroll
      for (int f = 0; f < 4; ++f) {
#pragma unroll
        for (int r = 0; r < 4; ++r) {
          st[f][r] = exp2_fast(st[f][r] - mcur);
          ls += st[f][r];
        }
      }
      ls += __shfl_xor(ls, 16);
      ls += __shfl_xor(ls, 32);
      l_run += ls;
    }
    // ---- PV B-operand built IN-REGISTER (zero exchange) ----
    union { uint4 u; bf16x8 bb; } pb0, pb1;
    pb0.u.x = cvt_pk_bf16(st[0][0], st[0][1]);
    pb0.u.y = cvt_pk_bf16(st[0][2], st[0][3]);
    pb0.u.z = cvt_pk_bf16(st[1][0], st[1][1]);
    pb0.u.w = cvt_pk_bf16(st[1][2], st[1][3]);
    pb1.u.x = cvt_pk_bf16(st[2][0], st[2][1]);
    pb1.u.y = cvt_pk_bf16(st[2][2], st[2][3]);
    pb1.u.z = cvt_pk_bf16(st[3][0], st[3][1]);
    pb1.u.w = cvt_pk_bf16(st[3][2], st[3][3]);
    // PV: Y^T[d][q] += Vt * P^T
    __builtin_amdgcn_s_setprio(1);
#pragma unroll
    for (int mfd = 0; mfd < 4; ++mfd) {
      const int vrow = mfd * 16 + q;
      const int swz = asb(vrow);
      const bf16x8 v0 = ld16(Vsm + ((vrow * 128 + g * 16) ^ swz));
      const bf16x8 v1 = ld16(Vsm + ((vrow * 128 + 64 + g * 16) ^ swz));
      yt[mfd] = mfma16(v0, pb0.bb, yt[mfd]);
      yt[mfd] = mfma16(v1, pb1.bb, yt[mfd]);
    }
    __builtin_amdgcn_s_setprio(0);
  };

  auto epilogue = [&](float l_run, const f32x4* yt, int qw) {
    const float inv = 1.f / l_run;
    const int qr = qw + q;
    unsigned short* yp = Yb + (size_t)(b * 2048 + qr) * 1024 + h * 64;
#pragma unroll
    for (int mfd = 0; mfd < 4; ++mfd) {
      uint2 o2;
      o2.x = cvt_pk_bf16(yt[mfd][0] * inv, yt[mfd][1] * inv);
      o2.y = cvt_pk_bf16(yt[mfd][2] * inv, yt[mfd][3] * inv);
      *(uint2*)(yp + mfd * 16 + g * 4) = o2;
    }
  };

  const int hi = 31 - pair, lo = pair;
  const int qw_hi = hi * 64 + w * 16;
  const int qw_lo = lo * 64 + w * 16;

  bf16x8 qh[2], ql[2];
#pragma unroll
  for (int kf = 0; kf < 2; ++kf) {
    qh[kf] = ld16(Qb + base + (size_t)(qw_hi + q) * 64 + kf * 32 + g * 8);
    ql[kf] = ld16(Qb + base + (size_t)(qw_lo + q) * 64 + kf * 32 + g * 8);
  }
  WAIT_VMCNT(0);  // drain Q loads so the stage-pipeline vmcnt counts stay exact

  float m_hi = -INFINITY, l_hi = 0.f, m_lo = -INFINITY, l_lo = 0.f;
  f32x4 yh[4] = {}, yl[4] = {};

  const int njv = hi + 1;  // 32 - pair staged tiles
  stage(0, 0);
  for (int j = 0; j < njv; ++j) {
    if (j + 1 < njv) {
      stage(j + 1, (j + 1) & 1);
      WAIT_VMCNT(4);
    } else {
      WAIT_VMCNT(0);
    }
    bar();

    const int kv0 = j << 6;
    const char* Ksm = smem + (j & 1) * 16384;
    const char* Vsm = Ksm + 8192;
    tile_step(qh, m_hi, l_hi, yh, qw_hi, kv0, Ksm, Vsm);
    if (j <= lo)  // block-uniform branch: lo tile's stream is a prefix
      tile_step(ql, m_lo, l_lo, yl, qw_lo, kv0, Ksm, Vsm);
    bar();  // all waves done reading buf before next stage overwrites
  }

  epilogue(l_hi, yh, qw_hi);
  epilogue(l_lo, yl, qw_lo);
}

extern "C" void kernel_launch(void* const* d_in, const int* in_sizes, int n_in,
                              void* d_out, int out_size, void* d_ws, size_t ws_size,
                              hipStream_t stream) {
  const float* x      = (const float*)d_in[0];
  const float* w_qkv  = (const float*)d_in[1];
  const float* b_qkv  = (const float*)d_in[2];
  const float* w_proj = (const float*)d_in[3];
  const float* b_proj = (const float*)d_in[4];
  float* out = (float*)d_out;
  char* ws = (char*)d_ws;

  unsigned short* xb  = (unsigned short*)(ws);                       // 16 MB x bf16
  unsigned short* wqb = (unsigned short*)(ws + (size_t)(16 << 20));  //  6 MB w_qkv bf16
  unsigned short* wpb = (unsigned short*)(ws + (size_t)(22 << 20));  //  2 MB w_proj bf16
  unsigned short* Qb  = (unsigned short*)(ws + (size_t)(24 << 20));  // 16 MB Q (pre-scaled log2e/8)
  unsigned short* Kb  = (unsigned short*)(ws + (size_t)(40 << 20));  // 16 MB K [bh][t][d]
  unsigned short* Vtb = (unsigned short*)(ws + (size_t)(56 << 20));  // 16 MB V^T [bh][d][t]
  unsigned short* Yb  = (unsigned short*)(ws + (size_t)(72 << 20));  // 16 MB attn out bf16

  cvt_all<<<12288, 256, 0, stream>>>(x, w_qkv, w_proj, xb, wqb, wpb);
  gemm_bt<3072, 1><<<dim3(64, 24), 256, 0, stream>>>(xb, wqb, b_qkv, nullptr, Qb, Kb, Vtb);
  attn_fwd<<<dim3(64, 16), 256, 0, stream>>>(Qb, Kb, Vtb, Yb);
  gemm_bt<1024, 0><<<dim3(64, 8), 256, 0, stream>>>(Yb, wpb, b_proj, out, nullptr, nullptr, nullptr);
}